// Round 13
// baseline (972.616 us; speedup 1.0000x reference)
//
#include <hip/hip_runtime.h>
#include <cmath>

#define THETA 10.0f

// Truncated SLAYER alpha kernel (tau=10, mult=1, K=77), computed in double
// to bit-match numpy's f64 -> f32 path.
__device__ __forceinline__ void init_srm(float* srm) {
    int tid = threadIdx.x;
    if (tid < 77) {
        double td = (double)tid;
        srm[tid] = (float)(td / 10.0 * exp(1.0 - td / 10.0));
    }
    __syncthreads();
}

// ---------------------------------------------------------------------------
// 0) coalesced LDS tiled transpose: in[M][T] -> out[T][M]
// ---------------------------------------------------------------------------
__global__ void transpose_kernel(const float* __restrict__ in, float* __restrict__ out,
                                 int M, int T) {
    __shared__ float tile[32][33];
    int mBase = blockIdx.x * 32;
    int tBase = blockIdx.y * 32;
    int tx = threadIdx.x, ty = threadIdx.y;  // block (32,8)
    for (int i = ty; i < 32; i += 8) {
        int m = mBase + i, t = tBase + tx;
        if (m < M && t < T) tile[i][tx] = in[(size_t)m * T + t];
    }
    __syncthreads();
    for (int i = ty; i < 32; i += 8) {
        int t = tBase + i, m = mBase + tx;
        if (t < T && m < M) out[(size_t)t * M + m] = tile[tx][i];
    }
}

// ---------------------------------------------------------------------------
// 1) PSP, guard-free head/body/tail full unroll. srm cached in 77 VGPRs.
//    Taps applied s = 0..76 ascending with fmaf -> bit-exact.
// ---------------------------------------------------------------------------
template <int TT>
__global__ void psp_kernel(const float* __restrict__ in, float* __restrict__ out,
                           int M) {
    __shared__ float srm_s[77];
    init_srm(srm_s);
    int tb = blockIdx.y * TT;
    int m = blockIdx.x * blockDim.x + threadIdx.x;
    if (m >= M) return;
    float c[77];
#pragma unroll
    for (int s = 0; s < 77; ++s) c[s] = srm_s[s];
    float acc[TT];
#pragma unroll
    for (int j = 0; j < TT; ++j) acc[j] = 0.f;
    // head: u = tb+k, k = TT-1..0  (s = j-k, 0..j per output)
#pragma unroll
    for (int k = TT - 1; k >= 0; --k) {
        float v = in[(size_t)(tb + k) * M + m];
#pragma unroll
        for (int j = k; j < TT; ++j) acc[j] = fmaf(v, c[j - k], acc[j]);
    }
    // body: u = tb-s0, s0 = 1..77-TT  (all j valid, s = s0+j)
#pragma unroll
    for (int s0 = 1; s0 <= 77 - TT; ++s0) {
        int u = tb - s0;
        if (u >= 0) {
            float v = in[(size_t)u * M + m];
#pragma unroll
            for (int j = 0; j < TT; ++j) acc[j] = fmaf(v, c[s0 + j], acc[j]);
        }
    }
    // tail: u = tb-k, k = 78-TT..76  (j <= 76-k)
#pragma unroll
    for (int k = 78 - TT; k <= 76; ++k) {
        int u = tb - k;
        if (u >= 0) {
            float v = in[(size_t)u * M + m];
#pragma unroll
            for (int j = 0; j <= 76 - k; ++j) acc[j] = fmaf(v, c[k + j], acc[j]);
        }
    }
#pragma unroll
    for (int j = 0; j < TT; ++j) out[(size_t)(tb + j) * M + m] = acc[j];
}

// ---------------------------------------------------------------------------
// 2) fused PSP + 2x2 sum-pool * 2.75, guard-free; pool pairs loaded as
//    float2 (b64 -> bank-conflict-free; stride-2 b32 was 4-way on even
//    banks). Same values, same (p0+p1)+(p2+p3) order -> bit-exact.
// ---------------------------------------------------------------------------
template <int TT>
__global__ void psppool_kernel(const float* __restrict__ in, float* __restrict__ out,
                               int NC, int Hin, int Win) {
    __shared__ float srm_s[77];
    init_srm(srm_s);
    int Ho = Hin >> 1, Wo = Win >> 1;
    int Mout = NC * Ho * Wo;
    int Min = NC * Hin * Win;
    int tb = blockIdx.y * TT;
    int mo = blockIdx.x * blockDim.x + threadIdx.x;
    if (mo >= Mout) return;
    int X = mo % Wo;
    int Y = (mo / Wo) % Ho;
    int nc = mo / (Wo * Ho);
    int base = nc * Hin * Win + (2 * Y) * Win + 2 * X;  // even -> 8B aligned
    float c[77];
#pragma unroll
    for (int s = 0; s < 77; ++s) c[s] = srm_s[s];
    float acc[TT];
#pragma unroll
    for (int j = 0; j < TT; ++j) acc[j] = 0.f;
#pragma unroll
    for (int k = TT - 1; k >= 0; --k) {
        const float* p = in + (size_t)(tb + k) * Min + base;
        float2 a0 = *reinterpret_cast<const float2*>(p);
        float2 a1 = *reinterpret_cast<const float2*>(p + Win);
        float v = (a0.x + a0.y) + (a1.x + a1.y);
#pragma unroll
        for (int j = k; j < TT; ++j) acc[j] = fmaf(c[j - k], v, acc[j]);
    }
#pragma unroll
    for (int s0 = 1; s0 <= 77 - TT; ++s0) {
        int u = tb - s0;
        if (u >= 0) {
            const float* p = in + (size_t)u * Min + base;
            float2 a0 = *reinterpret_cast<const float2*>(p);
            float2 a1 = *reinterpret_cast<const float2*>(p + Win);
            float v = (a0.x + a0.y) + (a1.x + a1.y);
#pragma unroll
            for (int j = 0; j < TT; ++j) acc[j] = fmaf(c[s0 + j], v, acc[j]);
        }
    }
#pragma unroll
    for (int k = 78 - TT; k <= 76; ++k) {
        int u = tb - k;
        if (u >= 0) {
            const float* p = in + (size_t)u * Min + base;
            float2 a0 = *reinterpret_cast<const float2*>(p);
            float2 a1 = *reinterpret_cast<const float2*>(p + Win);
            float v = (a0.x + a0.y) + (a1.x + a1.y);
#pragma unroll
            for (int j = 0; j <= 76 - k; ++j) acc[j] = fmaf(c[k + j], v, acc[j]);
        }
    }
#pragma unroll
    for (int j = 0; j < TT; ++j)
        out[(size_t)(tb + j) * Mout + mo] = acc[j] * 2.75f;  // 1.1*theta/4
}

// ---------------------------------------------------------------------------
// 3a) conv1 v4: (2->16, 5x5, pad1). Padded 36x36 input + transposed weights
//     [tap][o] in LDS (float4 reads). 4 rows/thread. Bit-exact tap order.
// ---------------------------------------------------------------------------
__global__ __launch_bounds__(256) void conv1_v4(const float* __restrict__ in,
                                                const float* __restrict__ w,
                                                float* __restrict__ out) {
    __shared__ float s_in[2592];   // 2 * 36 * 36, zero-padded border
    __shared__ float s_w[800];     // [tap 0..49][o 0..15]
    int n = blockIdx.x, t = blockIdx.y, tid = threadIdx.x;
    const float* src = in + ((size_t)t * 8 + n) * 2312;  // 2*34*34
    for (int idx = tid; idx < 2592; idx += 256) {
        int ch = idx / 1296, rem = idx % 1296;
        int r = rem / 36, col = rem % 36;
        float v = 0.f;
        if (r >= 1 && r <= 34 && col >= 1 && col <= 34)
            v = src[ch * 1156 + (r - 1) * 34 + (col - 1)];
        s_in[idx] = v;
    }
    for (int idx = tid; idx < 800; idx += 256) {
        int tap = idx >> 4, o = idx & 15;
        s_w[tap * 16 + o] = w[o * 50 + tap];
    }
    __syncthreads();
    int x = tid & 31, y0 = tid >> 5;  // rows y0, y0+8, y0+16, y0+24
    float acc[4][16];
#pragma unroll
    for (int q = 0; q < 4; ++q)
#pragma unroll
        for (int o = 0; o < 16; ++o) acc[q][o] = 0.f;
#pragma unroll
    for (int i = 0; i < 2; ++i) {
#pragma unroll
        for (int ky = 0; ky < 5; ++ky) {
#pragma unroll
            for (int kx = 0; kx < 5; ++kx) {
                int tap = i * 25 + ky * 5 + kx;
                float v[4];
#pragma unroll
                for (int q = 0; q < 4; ++q)
                    v[q] = s_in[i * 1296 + (y0 + 8 * q + ky) * 36 + (x + kx)];
                const float4* wp = (const float4*)&s_w[tap * 16];
#pragma unroll
                for (int oq = 0; oq < 4; ++oq) {
                    float4 w4 = wp[oq];
#pragma unroll
                    for (int q = 0; q < 4; ++q) {
                        acc[q][oq * 4 + 0] = fmaf(v[q], w4.x, acc[q][oq * 4 + 0]);
                        acc[q][oq * 4 + 1] = fmaf(v[q], w4.y, acc[q][oq * 4 + 1]);
                        acc[q][oq * 4 + 2] = fmaf(v[q], w4.z, acc[q][oq * 4 + 2]);
                        acc[q][oq * 4 + 3] = fmaf(v[q], w4.w, acc[q][oq * 4 + 3]);
                    }
                }
            }
        }
    }
    float* dst = out + ((size_t)t * 8 + n) * 16384;  // 16*32*32
#pragma unroll
    for (int q = 0; q < 4; ++q) {
        int y = y0 + 8 * q;
#pragma unroll
        for (int o = 0; o < 16; ++o) dst[o * 1024 + y * 32 + x] = acc[q][o];
    }
}

// ---------------------------------------------------------------------------
// 3b) conv2 v4: 16->32, 3x3, pad1, 16x16. o-split 2. Input rows padded to
//     STRIDE 24 floats: row bank-starts (24y)%32 = {0,24,16,8} -> the four
//     16-wide lane ranges tile 32 banks exactly twice = conflict-free
//     (stride 18 was 3-way on some banks: 5.5M conflict cycles measured).
//     Weights via wave-uniform global (scalar pipe). Bit-exact tap order.
// ---------------------------------------------------------------------------
__global__ __launch_bounds__(256) void conv2_v4(const float* __restrict__ in,
                                                const float* __restrict__ w,
                                                float* __restrict__ out) {
    __shared__ float s_in[16 * 18 * 24];  // rows padded 18 -> 24
    int n = blockIdx.x, t = blockIdx.y, ob = blockIdx.z * 16;
    int tid = threadIdx.x;
    const float* src = in + ((size_t)t * 8 + n) * 4096;  // 16*16*16
    for (int idx = tid; idx < 5184; idx += 256) {
        int c = idx / 324, rem = idx % 324;
        int r = rem / 18, col = rem % 18;
        float v = 0.f;
        if (r >= 1 && r <= 16 && col >= 1 && col <= 16)
            v = src[c * 256 + (r - 1) * 16 + (col - 1)];
        s_in[c * 432 + r * 24 + col] = v;  // cols 18..23 unused
    }
    __syncthreads();
    int x = tid & 15, y = tid >> 4;
    float acc[16];
#pragma unroll
    for (int o = 0; o < 16; ++o) acc[o] = 0.f;
    for (int i = 0; i < 16; ++i) {
        const float* base = &s_in[i * 432 + y * 24 + x];
        float vv[9];
#pragma unroll
        for (int ky = 0; ky < 3; ++ky)
#pragma unroll
            for (int kx = 0; kx < 3; ++kx) vv[ky * 3 + kx] = base[ky * 24 + kx];
#pragma unroll
        for (int tap = 0; tap < 9; ++tap) {
            float v = vv[tap];
            const float* wp = w + (size_t)ob * 144 + i * 9 + tap;  // uniform
#pragma unroll
            for (int o = 0; o < 16; ++o)
                acc[o] = fmaf(v, wp[o * 144], acc[o]);
        }
    }
    float* dst = out + (((size_t)t * 8 + n) * 32 + ob) * 256;
#pragma unroll
    for (int o = 0; o < 16; ++o) dst[o * 256 + tid] = acc[o];
}

// ---------------------------------------------------------------------------
// 3c) conv3: 32->64, 3x3, pad1, 8x8. Block = (4 n's) x (t) x (o-split 4).
//     s_in unpadded + per-pos tap masks; weights scalar. (Reads are a
//     constant-shifted 64-lane window -> already 2-way/free.)
// ---------------------------------------------------------------------------
__global__ __launch_bounds__(256) void conv3_v3(const float* __restrict__ in,
                                                const float* __restrict__ w,
                                                float* __restrict__ out) {
    __shared__ float s_in[8192];   // 4n * 32i * 64
    int n0 = blockIdx.x * 4, t = blockIdx.y, ob = blockIdx.z * 16;
    int tid = threadIdx.x;
    const float* src = in + ((size_t)t * 16384 + n0 * 2048);
    for (int i = tid; i < 8192; i += 256) s_in[i] = src[i];
    __syncthreads();
    int ln = tid >> 6;             // local n 0..3
    int pos = tid & 63;            // y*8+x
    int y = pos >> 3, x = pos & 7;
    bool mask[9];
    int off[9];
#pragma unroll
    for (int ky = 0; ky < 3; ++ky) {
        int iy = y + ky - 1;
        bool ry = (unsigned)iy < 8u;
#pragma unroll
        for (int kx = 0; kx < 3; ++kx) {
            int ix = x + kx - 1;
            bool ok = ry && ((unsigned)ix < 8u);
            mask[ky * 3 + kx] = ok;
            off[ky * 3 + kx] = ok ? (iy * 8 + ix) : 0;
        }
    }
    const float* base = &s_in[ln * 2048];
    float acc[16];
#pragma unroll
    for (int o = 0; o < 16; ++o) acc[o] = 0.f;
    for (int i = 0; i < 32; ++i) {
        const float* ip = base + i * 64;
        float vv[9];
#pragma unroll
        for (int tap = 0; tap < 9; ++tap)
            vv[tap] = mask[tap] ? ip[off[tap]] : 0.f;
#pragma unroll
        for (int tap = 0; tap < 9; ++tap) {
            float v = vv[tap];
            const float* wp = w + (size_t)ob * 288 + i * 9 + tap;  // uniform
#pragma unroll
            for (int o = 0; o < 16; ++o)
                acc[o] = fmaf(v, wp[o * 288], acc[o]);
        }
    }
    float* dst = out + (((size_t)t * 8 + n0 + ln) * 64 + ob) * 64;
#pragma unroll
    for (int o = 0; o < 16; ++o) dst[o * 64 + pos] = acc[o];
}

// ---------------------------------------------------------------------------
// 4) LIF spike scan, chunked loads (300 = 30*10), double-buffered.
//    64-thread blocks spread low-M scans across CUs.
// ---------------------------------------------------------------------------
template <int CH>
__global__ void spike_kernel(float* __restrict__ u, int M, int T) {
    int m = blockIdx.x * blockDim.x + threadIdx.x;
    if (m >= M) return;
    float ref[11];
#pragma unroll
    for (int k = 0; k < 11; ++k)
        ref[k] = (float)(-20.0 * (double)k * exp(1.0 - (double)k));
    float r[11];
#pragma unroll
    for (int k = 0; k < 11; ++k) r[k] = 0.f;
    float a[CH], b[CH];
#pragma unroll
    for (int j = 0; j < CH; ++j) a[j] = u[(size_t)j * M + m];
    int NC = T / CH;
    for (int c = 0; c < NC; ++c) {
        if (c + 1 < NC) {
#pragma unroll
            for (int j = 0; j < CH; ++j)
                b[j] = u[(size_t)((c + 1) * CH + j) * M + m];
        }
#pragma unroll
        for (int j = 0; j < CH; ++j) {
            float ue = a[j] + r[0];
            float s = (ue >= THETA) ? 1.0f : 0.0f;
            u[(size_t)(c * CH + j) * M + m] = s;
#pragma unroll
            for (int k = 0; k < 10; ++k) r[k] = fmaf(s, ref[k + 1], r[k + 1]);
        }
#pragma unroll
        for (int j = 0; j < CH; ++j) a[j] = b[j];
    }
}

// ---------------------------------------------------------------------------
// 5) dense: einsum nchwt,ochw->not  (per (t,n) block; 4096-long dot x 10)
// ---------------------------------------------------------------------------
__global__ void dense_kernel(const float* __restrict__ p, const float* __restrict__ wfc,
                             float* __restrict__ out) {
    int n = blockIdx.x;   // 0..7
    int t = blockIdx.y;   // 0..299
    int tid = threadIdx.x;
    const float* row = p + ((size_t)t * 8 + n) * 4096;
    float acc[10];
#pragma unroll
    for (int o = 0; o < 10; ++o) acc[o] = 0.f;
    for (int j = tid; j < 4096; j += 256) {
        float v = row[j];
#pragma unroll
        for (int o = 0; o < 10; ++o) acc[o] = fmaf(v, wfc[o * 4096 + j], acc[o]);
    }
    __shared__ float red[4][10];
#pragma unroll
    for (int o = 0; o < 10; ++o) {
        float a = acc[o];
        for (int off = 32; off > 0; off >>= 1) a += __shfl_down(a, off, 64);
        acc[o] = a;
    }
    int wave = tid >> 6, lane = tid & 63;
    if (lane == 0) {
#pragma unroll
        for (int o = 0; o < 10; ++o) red[wave][o] = acc[o];
    }
    __syncthreads();
    if (tid < 10) {
        float a = (red[0][tid] + red[1][tid]) + (red[2][tid] + red[3][tid]);
        out[((size_t)t * 8 + n) * 10 + tid] = a;
    }
}

// ---------------------------------------------------------------------------
// 6) final spike scan (chunked loads), writes d_out in (n,10,1,1,T) layout
// ---------------------------------------------------------------------------
template <int CH>
__global__ void spike_out_kernel(const float* __restrict__ u, float* __restrict__ out,
                                 int M, int T) {
    int m = blockIdx.x * blockDim.x + threadIdx.x;
    if (m >= M) return;
    float ref[11];
#pragma unroll
    for (int k = 0; k < 11; ++k)
        ref[k] = (float)(-20.0 * (double)k * exp(1.0 - (double)k));
    float r[11];
#pragma unroll
    for (int k = 0; k < 11; ++k) r[k] = 0.f;
    float a[CH], b[CH];
#pragma unroll
    for (int j = 0; j < CH; ++j) a[j] = u[(size_t)j * M + m];
    int NC = T / CH;
    for (int c = 0; c < NC; ++c) {
        if (c + 1 < NC) {
#pragma unroll
            for (int j = 0; j < CH; ++j)
                b[j] = u[(size_t)((c + 1) * CH + j) * M + m];
        }
#pragma unroll
        for (int j = 0; j < CH; ++j) {
            float ue = a[j] + r[0];
            float s = (ue >= THETA) ? 1.0f : 0.0f;
            out[(size_t)m * T + c * CH + j] = s;
#pragma unroll
            for (int k = 0; k < 10; ++k) r[k] = fmaf(s, ref[k + 1], r[k + 1]);
        }
#pragma unroll
        for (int j = 0; j < CH; ++j) a[j] = b[j];
    }
}

// ---------------------------------------------------------------------------
extern "C" void kernel_launch(void* const* d_in, const int* in_sizes, int n_in,
                              void* d_out, int out_size, void* d_ws, size_t ws_size,
                              hipStream_t stream) {
    const float* x   = (const float*)d_in[0];  // (8,2,34,34,300)
    const float* w1  = (const float*)d_in[1];  // (16,2,5,5,1)
    const float* w2  = (const float*)d_in[2];  // (32,16,3,3,1)
    const float* w3  = (const float*)d_in[3];  // (64,32,3,3,1)
    const float* wfc = (const float*)d_in[4];  // (10,64,8,8)
    float* outp = (float*)d_out;               // (8,10,1,1,300)

    float* slotB = (float*)d_ws;               // 39,321,600 floats
    float* slotA = slotB + 39321600;           // 19,660,800 floats
    const int T = 300;
    dim3 blk(256);
    dim3 blk64(64);
    constexpr int TT = 20;                      // 300 = 15 * 20
    constexpr int CH = 10;                      // 300 = 30 * 10

    // 0. xT = transpose(x): [18496][300] -> [300][18496], into slotB
    transpose_kernel<<<dim3(578, 10), dim3(32, 8), 0, stream>>>(x, slotB, 18496, T);
    // 1. p0 = psp(xT) -> slotA   M0 = 18496
    psp_kernel<TT><<<dim3(73, 15), blk, 0, stream>>>(slotB, slotA, 18496);
    // 2. u1 = conv1(p0) -> slotB   (8,16,32,32)
    conv1_v4<<<dim3(8, T), blk, 0, stream>>>(slotA, w1, slotB);
    // 3. s1 = spike(u1) in-place, M=131072
    spike_kernel<CH><<<dim3(2048), blk64, 0, stream>>>(slotB, 131072, T);
    // 4. u2 = pool(psp(s1)) -> slotA   M=32768
    psppool_kernel<TT><<<dim3(128, 15), blk, 0, stream>>>(slotB, slotA, 8 * 16, 32, 32);
    // 5. s2 = spike(u2)
    spike_kernel<CH><<<dim3(512), blk64, 0, stream>>>(slotA, 32768, T);
    // 6. p2 = psp(s2) -> slotB
    psp_kernel<TT><<<dim3(128, 15), blk, 0, stream>>>(slotA, slotB, 32768);
    // 7. u3 = conv2(p2) -> slotA   (8,32,16,16)
    conv2_v4<<<dim3(8, T, 2), blk, 0, stream>>>(slotB, w2, slotA);
    // 8. s3 = spike(u3), M=65536
    spike_kernel<CH><<<dim3(1024), blk64, 0, stream>>>(slotA, 65536, T);
    // 9. u4 = pool(psp(s3)) -> slotB   M=16384
    psppool_kernel<TT><<<dim3(64, 15), blk, 0, stream>>>(slotA, slotB, 8 * 32, 16, 16);
    // 10. s4 = spike(u4)
    spike_kernel<CH><<<dim3(256), blk64, 0, stream>>>(slotB, 16384, T);
    // 11. p4 = psp(s4) -> slotA
    psp_kernel<TT><<<dim3(64, 15), blk, 0, stream>>>(slotB, slotA, 16384);
    // 12. u5 = conv3(p4) -> slotB   (8,64,8,8)
    conv3_v3<<<dim3(2, T, 4), blk, 0, stream>>>(slotA, w3, slotB);
    // 13. s5 = spike(u5), M=32768
    spike_kernel<CH><<<dim3(512), blk64, 0, stream>>>(slotB, 32768, T);
    // 14. p5 = psp(s5) -> slotA
    psp_kernel<TT><<<dim3(128, 15), blk, 0, stream>>>(slotB, slotA, 32768);
    // 15. u6 = dense(p5, wfc) -> slotB  [T][8][10]
    dense_kernel<<<dim3(8, T), blk, 0, stream>>>(slotA, wfc, slotB);
    // 16. out = spike(u6), reference (n,o,t) layout
    spike_out_kernel<CH><<<dim3(2), dim3(64), 0, stream>>>(slotB, outp, 80, T);
}

// Round 14
// 830.161 us; speedup vs baseline: 1.1716x; 1.1716x over previous
//
#include <hip/hip_runtime.h>
#include <cmath>

#define THETA 10.0f

// Truncated SLAYER alpha kernel (tau=10, mult=1, K=77), computed in double
// to bit-match numpy's f64 -> f32 path.
__device__ __forceinline__ void init_srm(float* srm) {
    int tid = threadIdx.x;
    if (tid < 77) {
        double td = (double)tid;
        srm[tid] = (float)(td / 10.0 * exp(1.0 - td / 10.0));
    }
    __syncthreads();
}

// ---------------------------------------------------------------------------
// 0) coalesced LDS tiled transpose: in[M][T] -> out[T][M]
// ---------------------------------------------------------------------------
__global__ void transpose_kernel(const float* __restrict__ in, float* __restrict__ out,
                                 int M, int T) {
    __shared__ float tile[32][33];
    int mBase = blockIdx.x * 32;
    int tBase = blockIdx.y * 32;
    int tx = threadIdx.x, ty = threadIdx.y;  // block (32,8)
    for (int i = ty; i < 32; i += 8) {
        int m = mBase + i, t = tBase + tx;
        if (m < M && t < T) tile[i][tx] = in[(size_t)m * T + t];
    }
    __syncthreads();
    for (int i = ty; i < 32; i += 8) {
        int t = tBase + i, m = mBase + tx;
        if (t < T && m < M) out[(size_t)t * M + m] = tile[tx][i];
    }
}

// ---------------------------------------------------------------------------
// 1) PSP f32-input, guard-free head/body/tail full unroll; srm in 77 VGPRs.
//    Taps applied s = 0..76 ascending with fmaf -> bit-exact.
// ---------------------------------------------------------------------------
template <int TT>
__global__ void psp_kernel(const float* __restrict__ in, float* __restrict__ out,
                           int M) {
    __shared__ float srm_s[77];
    init_srm(srm_s);
    int tb = blockIdx.y * TT;
    int m = blockIdx.x * blockDim.x + threadIdx.x;
    if (m >= M) return;
    float c[77];
#pragma unroll
    for (int s = 0; s < 77; ++s) c[s] = srm_s[s];
    float acc[TT];
#pragma unroll
    for (int j = 0; j < TT; ++j) acc[j] = 0.f;
#pragma unroll
    for (int k = TT - 1; k >= 0; --k) {
        float v = in[(size_t)(tb + k) * M + m];
#pragma unroll
        for (int j = k; j < TT; ++j) acc[j] = fmaf(v, c[j - k], acc[j]);
    }
#pragma unroll
    for (int s0 = 1; s0 <= 77 - TT; ++s0) {
        int u = tb - s0;
        if (u >= 0) {
            float v = in[(size_t)u * M + m];
#pragma unroll
            for (int j = 0; j < TT; ++j) acc[j] = fmaf(v, c[s0 + j], acc[j]);
        }
    }
#pragma unroll
    for (int k = 78 - TT; k <= 76; ++k) {
        int u = tb - k;
        if (u >= 0) {
            float v = in[(size_t)u * M + m];
#pragma unroll
            for (int j = 0; j <= 76 - k; ++j) acc[j] = fmaf(v, c[k + j], acc[j]);
        }
    }
#pragma unroll
    for (int j = 0; j < TT; ++j) out[(size_t)(tb + j) * M + m] = acc[j];
}

// ---------------------------------------------------------------------------
// 1b) PSP u8-input (spikes stored as bytes, 0/1 exact; cvt is exact ->
//     bit-identical fma stream). 4x less read traffic.
// ---------------------------------------------------------------------------
template <int TT>
__global__ void psp_u8_kernel(const unsigned char* __restrict__ in,
                              float* __restrict__ out, int M) {
    __shared__ float srm_s[77];
    init_srm(srm_s);
    int tb = blockIdx.y * TT;
    int m = blockIdx.x * blockDim.x + threadIdx.x;
    if (m >= M) return;
    float c[77];
#pragma unroll
    for (int s = 0; s < 77; ++s) c[s] = srm_s[s];
    float acc[TT];
#pragma unroll
    for (int j = 0; j < TT; ++j) acc[j] = 0.f;
#pragma unroll
    for (int k = TT - 1; k >= 0; --k) {
        float v = (float)in[(size_t)(tb + k) * M + m];
#pragma unroll
        for (int j = k; j < TT; ++j) acc[j] = fmaf(v, c[j - k], acc[j]);
    }
#pragma unroll
    for (int s0 = 1; s0 <= 77 - TT; ++s0) {
        int u = tb - s0;
        if (u >= 0) {
            float v = (float)in[(size_t)u * M + m];
#pragma unroll
            for (int j = 0; j < TT; ++j) acc[j] = fmaf(v, c[s0 + j], acc[j]);
        }
    }
#pragma unroll
    for (int k = 78 - TT; k <= 76; ++k) {
        int u = tb - k;
        if (u >= 0) {
            float v = (float)in[(size_t)u * M + m];
#pragma unroll
            for (int j = 0; j <= 76 - k; ++j) acc[j] = fmaf(v, c[k + j], acc[j]);
        }
    }
#pragma unroll
    for (int j = 0; j < TT; ++j) out[(size_t)(tb + j) * M + m] = acc[j];
}

// ---------------------------------------------------------------------------
// 2) fused PSP + 2x2 sum-pool * 2.75, u8 spikes input. Quad-sum is an exact
//    integer 0..4 in both int and f32 paths -> value-identical -> bit-exact
//    downstream. uchar2 paired loads.
// ---------------------------------------------------------------------------
template <int TT>
__global__ void psppool_u8_kernel(const unsigned char* __restrict__ in,
                                  float* __restrict__ out,
                                  int NC, int Hin, int Win) {
    __shared__ float srm_s[77];
    init_srm(srm_s);
    int Ho = Hin >> 1, Wo = Win >> 1;
    int Mout = NC * Ho * Wo;
    int Min = NC * Hin * Win;
    int tb = blockIdx.y * TT;
    int mo = blockIdx.x * blockDim.x + threadIdx.x;
    if (mo >= Mout) return;
    int X = mo % Wo;
    int Y = (mo / Wo) % Ho;
    int nc = mo / (Wo * Ho);
    int base = nc * Hin * Win + (2 * Y) * Win + 2 * X;  // even -> 2B aligned
    float c[77];
#pragma unroll
    for (int s = 0; s < 77; ++s) c[s] = srm_s[s];
    float acc[TT];
#pragma unroll
    for (int j = 0; j < TT; ++j) acc[j] = 0.f;
#pragma unroll
    for (int k = TT - 1; k >= 0; --k) {
        const unsigned char* p = in + (size_t)(tb + k) * Min + base;
        uchar2 a0 = *reinterpret_cast<const uchar2*>(p);
        uchar2 a1 = *reinterpret_cast<const uchar2*>(p + Win);
        float v = (float)((int)a0.x + (int)a0.y + (int)a1.x + (int)a1.y);
#pragma unroll
        for (int j = k; j < TT; ++j) acc[j] = fmaf(c[j - k], v, acc[j]);
    }
#pragma unroll
    for (int s0 = 1; s0 <= 77 - TT; ++s0) {
        int u = tb - s0;
        if (u >= 0) {
            const unsigned char* p = in + (size_t)u * Min + base;
            uchar2 a0 = *reinterpret_cast<const uchar2*>(p);
            uchar2 a1 = *reinterpret_cast<const uchar2*>(p + Win);
            float v = (float)((int)a0.x + (int)a0.y + (int)a1.x + (int)a1.y);
#pragma unroll
            for (int j = 0; j < TT; ++j) acc[j] = fmaf(c[s0 + j], v, acc[j]);
        }
    }
#pragma unroll
    for (int k = 78 - TT; k <= 76; ++k) {
        int u = tb - k;
        if (u >= 0) {
            const unsigned char* p = in + (size_t)u * Min + base;
            uchar2 a0 = *reinterpret_cast<const uchar2*>(p);
            uchar2 a1 = *reinterpret_cast<const uchar2*>(p + Win);
            float v = (float)((int)a0.x + (int)a0.y + (int)a1.x + (int)a1.y);
#pragma unroll
            for (int j = 0; j <= 76 - k; ++j) acc[j] = fmaf(c[k + j], v, acc[j]);
        }
    }
#pragma unroll
    for (int j = 0; j < TT; ++j)
        out[(size_t)(tb + j) * Mout + mo] = acc[j] * 2.75f;  // 1.1*theta/4
}

// ---------------------------------------------------------------------------
// 3a) conv1 v4: (2->16, 5x5, pad1). Padded 36x36 input + transposed weights
//     [tap][o] in LDS (float4 reads). 4 rows/thread. Bit-exact tap order.
// ---------------------------------------------------------------------------
__global__ __launch_bounds__(256) void conv1_v4(const float* __restrict__ in,
                                                const float* __restrict__ w,
                                                float* __restrict__ out) {
    __shared__ float s_in[2592];   // 2 * 36 * 36, zero-padded border
    __shared__ float s_w[800];     // [tap 0..49][o 0..15]
    int n = blockIdx.x, t = blockIdx.y, tid = threadIdx.x;
    const float* src = in + ((size_t)t * 8 + n) * 2312;  // 2*34*34
    for (int idx = tid; idx < 2592; idx += 256) {
        int ch = idx / 1296, rem = idx % 1296;
        int r = rem / 36, col = rem % 36;
        float v = 0.f;
        if (r >= 1 && r <= 34 && col >= 1 && col <= 34)
            v = src[ch * 1156 + (r - 1) * 34 + (col - 1)];
        s_in[idx] = v;
    }
    for (int idx = tid; idx < 800; idx += 256) {
        int tap = idx >> 4, o = idx & 15;
        s_w[tap * 16 + o] = w[o * 50 + tap];
    }
    __syncthreads();
    int x = tid & 31, y0 = tid >> 5;  // rows y0, y0+8, y0+16, y0+24
    float acc[4][16];
#pragma unroll
    for (int q = 0; q < 4; ++q)
#pragma unroll
        for (int o = 0; o < 16; ++o) acc[q][o] = 0.f;
#pragma unroll
    for (int i = 0; i < 2; ++i) {
#pragma unroll
        for (int ky = 0; ky < 5; ++ky) {
#pragma unroll
            for (int kx = 0; kx < 5; ++kx) {
                int tap = i * 25 + ky * 5 + kx;
                float v[4];
#pragma unroll
                for (int q = 0; q < 4; ++q)
                    v[q] = s_in[i * 1296 + (y0 + 8 * q + ky) * 36 + (x + kx)];
                const float4* wp = (const float4*)&s_w[tap * 16];
#pragma unroll
                for (int oq = 0; oq < 4; ++oq) {
                    float4 w4 = wp[oq];
#pragma unroll
                    for (int q = 0; q < 4; ++q) {
                        acc[q][oq * 4 + 0] = fmaf(v[q], w4.x, acc[q][oq * 4 + 0]);
                        acc[q][oq * 4 + 1] = fmaf(v[q], w4.y, acc[q][oq * 4 + 1]);
                        acc[q][oq * 4 + 2] = fmaf(v[q], w4.z, acc[q][oq * 4 + 2]);
                        acc[q][oq * 4 + 3] = fmaf(v[q], w4.w, acc[q][oq * 4 + 3]);
                    }
                }
            }
        }
    }
    float* dst = out + ((size_t)t * 8 + n) * 16384;  // 16*32*32
#pragma unroll
    for (int q = 0; q < 4; ++q) {
        int y = y0 + 8 * q;
#pragma unroll
        for (int o = 0; o < 16; ++o) dst[o * 1024 + y * 32 + x] = acc[q][o];
    }
}

// ---------------------------------------------------------------------------
// 3b) conv2 v3 (measured best: 145us): 16->32, 3x3, pad1, o-split 2.
//     Input padded 18x18 (stride 18 -- the 24-pad experiment showed the
//     conflict counter is only ~7% of time and cost occupancy). Weights via
//     wave-uniform global (scalar pipe). Bit-exact tap order.
// ---------------------------------------------------------------------------
__global__ __launch_bounds__(256) void conv2_v3(const float* __restrict__ in,
                                                const float* __restrict__ w,
                                                float* __restrict__ out) {
    __shared__ float s_in[5184];   // 16 * 18 * 18, zero-padded border
    int n = blockIdx.x, t = blockIdx.y, ob = blockIdx.z * 16;
    int tid = threadIdx.x;
    const float* src = in + ((size_t)t * 8 + n) * 4096;  // 16*16*16
    for (int idx = tid; idx < 5184; idx += 256) {
        int c = idx / 324, rem = idx % 324;
        int r = rem / 18, col = rem % 18;
        float v = 0.f;
        if (r >= 1 && r <= 16 && col >= 1 && col <= 16)
            v = src[c * 256 + (r - 1) * 16 + (col - 1)];
        s_in[idx] = v;
    }
    __syncthreads();
    int x = tid & 15, y = tid >> 4;
    float acc[16];
#pragma unroll
    for (int o = 0; o < 16; ++o) acc[o] = 0.f;
    for (int i = 0; i < 16; ++i) {
        const float* base = &s_in[i * 324 + y * 18 + x];
        float vv[9];
#pragma unroll
        for (int ky = 0; ky < 3; ++ky)
#pragma unroll
            for (int kx = 0; kx < 3; ++kx) vv[ky * 3 + kx] = base[ky * 18 + kx];
#pragma unroll
        for (int tap = 0; tap < 9; ++tap) {
            float v = vv[tap];
            const float* wp = w + (size_t)ob * 144 + i * 9 + tap;  // uniform
#pragma unroll
            for (int o = 0; o < 16; ++o)
                acc[o] = fmaf(v, wp[o * 144], acc[o]);
        }
    }
    float* dst = out + (((size_t)t * 8 + n) * 32 + ob) * 256;
#pragma unroll
    for (int o = 0; o < 16; ++o) dst[o * 256 + tid] = acc[o];
}

// ---------------------------------------------------------------------------
// 3c) conv3: 32->64, 3x3, pad1, 8x8. Block = (4 n's) x (t) x (o-split 4).
//     s_in unpadded + per-pos tap masks; weights scalar.
// ---------------------------------------------------------------------------
__global__ __launch_bounds__(256) void conv3_v3(const float* __restrict__ in,
                                                const float* __restrict__ w,
                                                float* __restrict__ out) {
    __shared__ float s_in[8192];   // 4n * 32i * 64
    int n0 = blockIdx.x * 4, t = blockIdx.y, ob = blockIdx.z * 16;
    int tid = threadIdx.x;
    const float* src = in + ((size_t)t * 16384 + n0 * 2048);
    for (int i = tid; i < 8192; i += 256) s_in[i] = src[i];
    __syncthreads();
    int ln = tid >> 6;             // local n 0..3
    int pos = tid & 63;            // y*8+x
    int y = pos >> 3, x = pos & 7;
    bool mask[9];
    int off[9];
#pragma unroll
    for (int ky = 0; ky < 3; ++ky) {
        int iy = y + ky - 1;
        bool ry = (unsigned)iy < 8u;
#pragma unroll
        for (int kx = 0; kx < 3; ++kx) {
            int ix = x + kx - 1;
            bool ok = ry && ((unsigned)ix < 8u);
            mask[ky * 3 + kx] = ok;
            off[ky * 3 + kx] = ok ? (iy * 8 + ix) : 0;
        }
    }
    const float* base = &s_in[ln * 2048];
    float acc[16];
#pragma unroll
    for (int o = 0; o < 16; ++o) acc[o] = 0.f;
    for (int i = 0; i < 32; ++i) {
        const float* ip = base + i * 64;
        float vv[9];
#pragma unroll
        for (int tap = 0; tap < 9; ++tap)
            vv[tap] = mask[tap] ? ip[off[tap]] : 0.f;
#pragma unroll
        for (int tap = 0; tap < 9; ++tap) {
            float v = vv[tap];
            const float* wp = w + (size_t)ob * 288 + i * 9 + tap;  // uniform
#pragma unroll
            for (int o = 0; o < 16; ++o)
                acc[o] = fmaf(v, wp[o * 288], acc[o]);
        }
    }
    float* dst = out + (((size_t)t * 8 + n0 + ln) * 64 + ob) * 64;
#pragma unroll
    for (int o = 0; o < 16; ++o) dst[o * 64 + pos] = acc[o];
}

// ---------------------------------------------------------------------------
// 4) LIF spike scan: reads f32 u, writes u8 spikes (0/1 exact; 4x less write
//    traffic). Chunked loads (300 = 30*10), double-buffered; 64-thr blocks.
// ---------------------------------------------------------------------------
template <int CH>
__global__ void spike_u8_kernel(const float* __restrict__ u,
                                unsigned char* __restrict__ sp, int M, int T) {
    int m = blockIdx.x * blockDim.x + threadIdx.x;
    if (m >= M) return;
    float ref[11];
#pragma unroll
    for (int k = 0; k < 11; ++k)
        ref[k] = (float)(-20.0 * (double)k * exp(1.0 - (double)k));
    float r[11];
#pragma unroll
    for (int k = 0; k < 11; ++k) r[k] = 0.f;
    float a[CH], b[CH];
#pragma unroll
    for (int j = 0; j < CH; ++j) a[j] = u[(size_t)j * M + m];
    int NC = T / CH;
    for (int c = 0; c < NC; ++c) {
        if (c + 1 < NC) {
#pragma unroll
            for (int j = 0; j < CH; ++j)
                b[j] = u[(size_t)((c + 1) * CH + j) * M + m];
        }
#pragma unroll
        for (int j = 0; j < CH; ++j) {
            float ue = a[j] + r[0];
            float s = (ue >= THETA) ? 1.0f : 0.0f;
            sp[(size_t)(c * CH + j) * M + m] = (unsigned char)(ue >= THETA);
#pragma unroll
            for (int k = 0; k < 10; ++k) r[k] = fmaf(s, ref[k + 1], r[k + 1]);
        }
#pragma unroll
        for (int j = 0; j < CH; ++j) a[j] = b[j];
    }
}

// ---------------------------------------------------------------------------
// 5) dense: einsum nchwt,ochw->not  (per (t,n) block; 4096-long dot x 10)
// ---------------------------------------------------------------------------
__global__ void dense_kernel(const float* __restrict__ p, const float* __restrict__ wfc,
                             float* __restrict__ out) {
    int n = blockIdx.x;   // 0..7
    int t = blockIdx.y;   // 0..299
    int tid = threadIdx.x;
    const float* row = p + ((size_t)t * 8 + n) * 4096;
    float acc[10];
#pragma unroll
    for (int o = 0; o < 10; ++o) acc[o] = 0.f;
    for (int j = tid; j < 4096; j += 256) {
        float v = row[j];
#pragma unroll
        for (int o = 0; o < 10; ++o) acc[o] = fmaf(v, wfc[o * 4096 + j], acc[o]);
    }
    __shared__ float red[4][10];
#pragma unroll
    for (int o = 0; o < 10; ++o) {
        float a = acc[o];
        for (int off = 32; off > 0; off >>= 1) a += __shfl_down(a, off, 64);
        acc[o] = a;
    }
    int wave = tid >> 6, lane = tid & 63;
    if (lane == 0) {
#pragma unroll
        for (int o = 0; o < 10; ++o) red[wave][o] = acc[o];
    }
    __syncthreads();
    if (tid < 10) {
        float a = (red[0][tid] + red[1][tid]) + (red[2][tid] + red[3][tid]);
        out[((size_t)t * 8 + n) * 10 + tid] = a;
    }
}

// ---------------------------------------------------------------------------
// 6) final spike scan (chunked loads), writes d_out in (n,10,1,1,T) layout
// ---------------------------------------------------------------------------
template <int CH>
__global__ void spike_out_kernel(const float* __restrict__ u, float* __restrict__ out,
                                 int M, int T) {
    int m = blockIdx.x * blockDim.x + threadIdx.x;
    if (m >= M) return;
    float ref[11];
#pragma unroll
    for (int k = 0; k < 11; ++k)
        ref[k] = (float)(-20.0 * (double)k * exp(1.0 - (double)k));
    float r[11];
#pragma unroll
    for (int k = 0; k < 11; ++k) r[k] = 0.f;
    float a[CH], b[CH];
#pragma unroll
    for (int j = 0; j < CH; ++j) a[j] = u[(size_t)j * M + m];
    int NC = T / CH;
    for (int c = 0; c < NC; ++c) {
        if (c + 1 < NC) {
#pragma unroll
            for (int j = 0; j < CH; ++j)
                b[j] = u[(size_t)((c + 1) * CH + j) * M + m];
        }
#pragma unroll
        for (int j = 0; j < CH; ++j) {
            float ue = a[j] + r[0];
            float s = (ue >= THETA) ? 1.0f : 0.0f;
            out[(size_t)m * T + c * CH + j] = s;
#pragma unroll
            for (int k = 0; k < 10; ++k) r[k] = fmaf(s, ref[k + 1], r[k + 1]);
        }
#pragma unroll
        for (int j = 0; j < CH; ++j) a[j] = b[j];
    }
}

// ---------------------------------------------------------------------------
extern "C" void kernel_launch(void* const* d_in, const int* in_sizes, int n_in,
                              void* d_out, int out_size, void* d_ws, size_t ws_size,
                              hipStream_t stream) {
    const float* x   = (const float*)d_in[0];  // (8,2,34,34,300)
    const float* w1  = (const float*)d_in[1];  // (16,2,5,5,1)
    const float* w2  = (const float*)d_in[2];  // (32,16,3,3,1)
    const float* w3  = (const float*)d_in[3];  // (64,32,3,3,1)
    const float* wfc = (const float*)d_in[4];  // (10,64,8,8)
    float* outp = (float*)d_out;               // (8,10,1,1,300)

    float* slotB = (float*)d_ws;               // 39,321,600 floats (157MB)
    float* slotA = slotB + 39321600;           // 19,660,800 floats (78.6MB)
    // u8 spike buffers carved from dead halves (lifetimes verified):
    unsigned char* s1_u8 = (unsigned char*)(slotA + 9830400);  // 39.3MB region
    unsigned char* sB_u8 = (unsigned char*)(slotB + 9830400);  // s2/s3/s4 region
    unsigned char* s5_u8 = (unsigned char*)slotA;              // 9.8MB region
    const int T = 300;
    dim3 blk(256);
    dim3 blk64(64);
    constexpr int TT = 20;                      // 300 = 15 * 20
    constexpr int CH = 10;                      // 300 = 30 * 10

    // 0. xT = transpose(x) -> slotB [22MB]
    transpose_kernel<<<dim3(578, 10), dim3(32, 8), 0, stream>>>(x, slotB, 18496, T);
    // 1. p0 = psp(xT) -> slotA [22MB]
    psp_kernel<TT><<<dim3(73, 15), blk, 0, stream>>>(slotB, slotA, 18496);
    // 2. u1 = conv1(p0) -> slotB [157MB]   (8,16,32,32)
    conv1_v4<<<dim3(8, T), blk, 0, stream>>>(slotA, w1, slotB);
    // 3. s1 = spike(u1) -> s1_u8 [39MB], M=131072
    spike_u8_kernel<CH><<<dim3(2048), blk64, 0, stream>>>(slotB, s1_u8, 131072, T);
    // 4. u2 = pool(psp(s1)) -> slotA[0..39MB], M=32768
    psppool_u8_kernel<TT><<<dim3(128, 15), blk, 0, stream>>>(s1_u8, slotA, 8 * 16, 32, 32);
    // 5. s2 = spike(u2) -> sB_u8 [9.8MB]
    spike_u8_kernel<CH><<<dim3(512), blk64, 0, stream>>>(slotA, sB_u8, 32768, T);
    // 6. p2 = psp(s2) -> slotB[0..39MB]
    psp_u8_kernel<TT><<<dim3(128, 15), blk, 0, stream>>>(sB_u8, slotB, 32768);
    // 7. u3 = conv2(p2) -> slotA [78.6MB]   (8,32,16,16)
    conv2_v3<<<dim3(8, T, 2), blk, 0, stream>>>(slotB, w2, slotA);
    // 8. s3 = spike(u3) -> sB_u8 [19.7MB], M=65536  (s2 dead)
    spike_u8_kernel<CH><<<dim3(1024), blk64, 0, stream>>>(slotA, sB_u8, 65536, T);
    // 9. u4 = pool(psp(s3)) -> slotB[0..19.7MB], M=16384
    psppool_u8_kernel<TT><<<dim3(64, 15), blk, 0, stream>>>(sB_u8, slotB, 8 * 32, 16, 16);
    // 10. s4 = spike(u4) -> sB_u8 [4.9MB]  (s3 dead; reads slotB[0..19.7MB])
    spike_u8_kernel<CH><<<dim3(256), blk64, 0, stream>>>(slotB, sB_u8, 16384, T);
    // 11. p4 = psp(s4) -> slotA[0..19.7MB]  (u3 dead)
    psp_u8_kernel<TT><<<dim3(64, 15), blk, 0, stream>>>(sB_u8, slotA, 16384);
    // 12. u5 = conv3(p4) -> slotB[0..39.3MB]  (ends exactly at sB_u8 start)
    conv3_v3<<<dim3(2, T, 4), blk, 0, stream>>>(slotA, w3, slotB);
    // 13. s5 = spike(u5) -> s5_u8 [9.8MB at slotA; p4 dead]
    spike_u8_kernel<CH><<<dim3(512), blk64, 0, stream>>>(slotB, s5_u8, 32768, T);
    // 14. p5 = psp(s5) -> slotB[0..39.3MB]  (u5 dead)
    psp_u8_kernel<TT><<<dim3(128, 15), blk, 0, stream>>>(s5_u8, slotB, 32768);
    // 15. u6 = dense(p5) -> slotA + 16M floats (clear of s5's 9.8MB)
    float* u6 = slotA + 16000000;
    dense_kernel<<<dim3(8, T), blk, 0, stream>>>(slotB, wfc, u6);
    // 16. out = spike(u6), reference (n,o,t) layout
    spike_out_kernel<CH><<<dim3(2), dim3(64), 0, stream>>>(u6, outp, 80, T);
}